// Round 2
// baseline (607.419 us; speedup 1.0000x reference)
//
#include <hip/hip_runtime.h>
#include <hip/hip_cooperative_groups.h>
#include <cstdint>

namespace cg = cooperative_groups;
typedef unsigned long long u64;

#define THRESH 0.5f
#define SIGMA 2.0f
#define MAXN 512    // LDS finalize capacity (N=500)
#define GRID 1024   // 256 CU x 4 blocks/CU -- co-residency guaranteed by
                    // __launch_bounds__(256,4): <=128 VGPR, 6.3KB LDS/block

// better(a,b): does a precede b in the reference's stable descending sort?
__device__ __forceinline__ bool better(float sa, int a, float sb, int b) {
    return (sa > sb) || (sa == sb && a < b);
}

// Deterministic per-mask score finalize. IDENTICAL expression everywhere it is
// used (phase-2 lane-0 and phase-3 LDS fill) -> bit-identical floats.
__device__ __forceinline__ float fscore(
    const double* __restrict__ pssum, const int* __restrict__ pcnt,
    const float* __restrict__ cate, int idx, float* __restrict__ sumOut)
{
    const double S = ((pssum[4*idx] + pssum[4*idx+1]) + pssum[4*idx+2]) + pssum[4*idx+3];
    const int C = ((pcnt[4*idx] + pcnt[4*idx+1]) + pcnt[4*idx+2]) + pcnt[4*idx+3];
    *sumOut = (float)C;
    return cate[idx] * (float)(S / (double)(C > 1 ? C : 1));
}

// ---------------------------------------------------------------------------
// Fused cooperative kernel: pack -> grid.sync -> label-sparse pairs+comp ->
// grid.sync -> final. Removes two launch/drain boundaries vs the 3-kernel
// version; everything else is expression-identical (absmax stays 0.0).
//
// Phase 1 (pack): grid-stride over N*4 quarter-mask tasks. Each iter a lane
// issues FOUR back-to-back float4 loads (4KB/wave in flight) -> latency-
// hidden HBM stream (131MB read = ~21us floor). Binarize + bit-pack via
// 64-lane __ballot (fixed pixel permutation, identical for all masks ->
// popcount(AND) intersections exact). fp64 partial soft-sums per task.
//
// Phase 2 (pairs): output depends ONLY on same-label pairs (~1.3k of 125k at
// 80 random classes). Grid-stride waves scan i<j slots with a wave-uniform
// label filter; a matched pair streams both 8KB packed masks from L2
// (coalesced dwordx4), popcount(AND), shuffle-reduce. Lane 0 finalizes both
// scores and folds comp in via device-scope atomicMax on IoU bits (IoU>=0 ->
// float bits monotonic; max order-independent -> deterministic).
//
// Phase 3 (final): block bI<N computes m = max over a of (d(a->b)^2 -
// comp[a]^2) and rank(b) = #better(a,b); out[rank] = score*exp(-sigma*m).
// ---------------------------------------------------------------------------
__global__ __launch_bounds__(256, 4) void k_fused(
    const float* __restrict__ preds, const float* __restrict__ cate,
    const int* __restrict__ labels, u64* __restrict__ packed,
    double* __restrict__ pssum, int* __restrict__ pcnt,
    unsigned* __restrict__ inter, unsigned* __restrict__ compU,
    float* __restrict__ out, int N, int HW)
{
    cg::grid_group gg = cg::this_grid();
    const int tid = threadIdx.x;
    const int wave = tid >> 6, lane = tid & 63;
    const int WORDS = HW >> 6;

    __shared__ double ls[4];
    __shared__ int lc[4];
    __shared__ float s_score[MAXN];
    __shared__ float s_sum[MAXN];
    __shared__ int s_label[MAXN];
    __shared__ float lm[4];
    __shared__ int lr[4];

    // ---- phase 1: pack ----------------------------------------------------
    if (blockIdx.x == 0) {                        // init comp maxes (bits of 0.0f)
        for (int t = tid; t < MAXN; t += 256) compU[t] = 0u;
    }
    const int ntask = N * 4;
    const int seg = HW >> 2;                      // 16384 px per quarter
    for (int task = blockIdx.x; task < ntask; task += gridDim.x) {
        const int i = task >> 2, sub = task & 3;
        const float* src = preds + (size_t)i * HW + (size_t)sub * seg;
        u64* dst = packed + (size_t)i * WORDS + (size_t)sub * (seg >> 6);
        double ssum = 0.0;
        int cnt = 0;
        const int iters = seg >> 12;              // 4096 px per block-iter
        for (int k = 0; k < iters; ++k) {
            const int base = (k << 12) + (wave << 10) + (lane << 2);
            const float4 v0 = *reinterpret_cast<const float4*>(src + base);
            const float4 v1 = *reinterpret_cast<const float4*>(src + base + 256);
            const float4 v2 = *reinterpret_cast<const float4*>(src + base + 512);
            const float4 v3 = *reinterpret_cast<const float4*>(src + base + 768);
            #pragma unroll
            for (int q = 0; q < 4; ++q) {
                const float4 v = (q == 0) ? v0 : (q == 1) ? v1 : (q == 2) ? v2 : v3;
                const bool b0 = v.x > THRESH, b1 = v.y > THRESH, b2 = v.z > THRESH, b3 = v.w > THRESH;
                const u64 m0 = __ballot(b0);
                const u64 m1 = __ballot(b1);
                const u64 m2 = __ballot(b2);
                const u64 m3 = __ballot(b3);
                if (lane < 4) {
                    const u64 m = (lane == 0) ? m0 : (lane == 1) ? m1 : (lane == 2) ? m2 : m3;
                    dst[(k << 6) + (wave << 4) + (q << 2) + lane] = m;
                }
                cnt += (int)b0 + (int)b1 + (int)b2 + (int)b3;
                ssum += (b0 ? (double)v.x : 0.0) + (b1 ? (double)v.y : 0.0)
                      + (b2 ? (double)v.z : 0.0) + (b3 ? (double)v.w : 0.0);
            }
        }
        for (int off = 32; off > 0; off >>= 1) {
            ssum += __shfl_down(ssum, off);
            cnt  += __shfl_down(cnt, off);
        }
        if (lane == 0) { ls[wave] = ssum; lc[wave] = cnt; }
        __syncthreads();
        if (tid == 0) {
            pssum[task] = ls[0] + ls[1] + ls[2] + ls[3];
            pcnt[task]  = lc[0] + lc[1] + lc[2] + lc[3];
        }
        __syncthreads();                          // ls/lc reused next task
    }
    __threadfence();
    gg.sync();

    // ---- phase 2: label-sparse pairwise intersections + comp --------------
    {
        const int wid = (blockIdx.x << 2) + wave;
        const int nw = gridDim.x << 2;
        const int NN = N * N;
        int i = wid / N;
        int j = wid - i * N;
        for (int p = wid; p < NN; p += nw) {
            if (j > i && labels[i] == labels[j]) {
                const u64* A = packed + (size_t)i * WORDS;
                const u64* B = packed + (size_t)j * WORDS;
                unsigned acc = 0;
                const int iters = WORDS >> 7;     // 8: lane covers 2 u64/iter
                #pragma unroll 2
                for (int k = 0; k < iters; ++k) {
                    const int idx = (k << 7) + (lane << 1);
                    const ulonglong2 a = *reinterpret_cast<const ulonglong2*>(A + idx);
                    const ulonglong2 b = *reinterpret_cast<const ulonglong2*>(B + idx);
                    acc += (unsigned)__popcll(a.x & b.x) + (unsigned)__popcll(a.y & b.y);
                }
                #pragma unroll
                for (int off = 32; off > 0; off >>= 1) acc += __shfl_down(acc, off);
                if (lane == 0) {
                    inter[(size_t)i * N + j] = acc;
                    float smi, smj;
                    const float si = fscore(pssum, pcnt, cate, i, &smi);
                    const float sj = fscore(pssum, pcnt, cate, j, &smj);
                    const int w = better(si, i, sj, j) ? j : i;   // suppressed
                    // fp32 add commutative -> bit-identical to phase 3's
                    // (s_sum[a] + sub) - inter regardless of which is better.
                    const float un = (smi + smj) - (float)acc;
                    const float iou = (float)acc / fmaxf(un, 1.0f);
                    atomicMax(&compU[w], __float_as_uint(iou));
                }
            }
            j += nw;
            while (j >= N) { j -= N; ++i; }
        }
    }
    __threadfence();
    gg.sync();

    // ---- phase 3: final ---------------------------------------------------
    const int bI = blockIdx.x;
    if (bI >= N) return;
    for (int idx = tid; idx < N; idx += 256) {
        float sm;
        s_score[idx] = fscore(pssum, pcnt, cate, idx, &sm);
        s_sum[idx] = sm;
        s_label[idx] = labels[idx];
    }
    __syncthreads();

    const float sb = s_score[bI], sub = s_sum[bI];
    const int lb = s_label[bI];
    float m = -3.0e38f;
    int r = 0;
    for (int a = tid; a < N; a += 256) {
        const bool bet = (a != bI) && better(s_score[a], a, sb, bI);
        r += (int)bet;
        float d = 0.0f;
        if (bet && s_label[a] == lb) {
            const int lo = a < bI ? a : bI, hi = a < bI ? bI : a;
            const float in = (float)inter[(size_t)lo * N + hi];
            const float un = s_sum[a] + sub - in;
            d = in / fmaxf(un, 1.0f);
        }
        const float ca = __uint_as_float(compU[a]);
        m = fmaxf(m, d * d - ca * ca);
    }
    for (int off = 32; off > 0; off >>= 1) {
        m = fmaxf(m, __shfl_down(m, off));
        r += __shfl_down(r, off);
    }
    if (lane == 0) { lm[wave] = m; lr[wave] = r; }
    __syncthreads();
    if (tid == 0) {
        const float mm = fmaxf(fmaxf(lm[0], lm[1]), fmaxf(lm[2], lm[3]));
        const int rank = lr[0] + lr[1] + lr[2] + lr[3];
        out[rank] = sb * expf(-SIGMA * mm);
    }
}

extern "C" void kernel_launch(void* const* d_in, const int* in_sizes, int n_in,
                              void* d_out, int out_size, void* d_ws, size_t ws_size,
                              hipStream_t stream)
{
    const float* preds  = (const float*)d_in[0];
    const float* cate   = (const float*)d_in[1];
    const int*   labels = (const int*)d_in[2];
    float* out = (float*)d_out;

    int N = in_sizes[1];
    int HW = in_sizes[0] / N;
    const int WORDS = HW >> 6;

    char* ws = (char*)d_ws;
    size_t off = 0;
    auto take = [&](size_t bytes) -> void* {
        void* p = ws + off;
        off = (off + bytes + 255) & ~(size_t)255;
        return p;
    };
    u64*      packed = (u64*)     take((size_t)N * WORDS * sizeof(u64));   // ~4.1 MB
    double*   pssum  = (double*)  take((size_t)N * 4 * sizeof(double));
    int*      pcnt   = (int*)     take((size_t)N * 4 * sizeof(int));
    unsigned* compU  = (unsigned*)take((size_t)MAXN * sizeof(unsigned));
    unsigned* inter  = (unsigned*)take((size_t)N * N * sizeof(unsigned));  // ~1 MB
    (void)ws_size; (void)n_in; (void)out_size;

    void* args[] = {
        (void*)&preds, (void*)&cate, (void*)&labels, (void*)&packed,
        (void*)&pssum, (void*)&pcnt, (void*)&inter, (void*)&compU,
        (void*)&out, (void*)&N, (void*)&HW
    };
    hipLaunchCooperativeKernel((const void*)k_fused, dim3(GRID), dim3(256),
                               args, 0, stream);
}

// Round 3
// 223.647 us; speedup vs baseline: 2.7160x; 2.7160x over previous
//
#include <hip/hip_runtime.h>
#include <cstdint>

typedef unsigned long long u64;

#define THRESH 0.5f
#define SIGMA 2.0f
#define MAXN 512    // LDS finalize capacity (N=500)

// better(a,b): does a precede b in the reference's stable descending sort?
__device__ __forceinline__ bool better(float sa, int a, float sb, int b) {
    return (sa > sb) || (sa == sb && a < b);
}

// ---------------------------------------------------------------------------
// K1: ONE block per mask (500 blocks x 256 thr, 2000 waves ~ 7.8/CU). Per iter
// each lane issues FOUR back-to-back float4 loads (4 KB/wave in flight) before
// any dependent compute -> latency-hidden HBM stream (131 MB read = ~21 us
// floor). Binarize + bit-pack via 64-lane __ballot (fixed pixel permutation,
// identical for all masks -> popcount(AND) intersections exact). fp64 soft-sum
// accumulated per lane, wave shfl-reduce, 4-wave LDS combine; block FINALIZES
// score[i]/sum[i] directly (computed once, stored -> downstream kernels just
// load floats; no redundant re-finalization, no cross-kernel fp identity
// concerns). Block 0 additionally zeroes compU (consumed in K2).
// NOTE: plain __launch_bounds__(256) -- round 2 showed that min-waves hints +
// fancy structure collapsed the allocator to 24 VGPRs, killing the 4-deep
// load pipeline. Keep the allocator free.
// ---------------------------------------------------------------------------
__global__ __launch_bounds__(256) void k_pack(
    const float* __restrict__ preds, const float* __restrict__ cate,
    u64* __restrict__ packed, float* __restrict__ scoreArr,
    float* __restrict__ sumArr, unsigned* __restrict__ compU, int HW)
{
    const int i = blockIdx.x;
    const int tid = threadIdx.x;
    if (i == 0) {                                 // init comp maxes (bits of 0.0f)
        for (int t = tid; t < MAXN; t += 256) compU[t] = 0u;
    }
    const float* src = preds + (size_t)i * HW;
    u64* dst = packed + (size_t)i * (HW >> 6);
    const int wave = tid >> 6, lane = tid & 63;
    double ssum = 0.0;
    int cnt = 0;
    const int iters = HW >> 12;                   // 16: 4096 px per block-iter
    for (int k = 0; k < iters; ++k) {
        const int base = (k << 12) + (wave << 10) + (lane << 2);
        const float4 v0 = *reinterpret_cast<const float4*>(src + base);
        const float4 v1 = *reinterpret_cast<const float4*>(src + base + 256);
        const float4 v2 = *reinterpret_cast<const float4*>(src + base + 512);
        const float4 v3 = *reinterpret_cast<const float4*>(src + base + 768);
        #pragma unroll
        for (int q = 0; q < 4; ++q) {
            const float4 v = (q == 0) ? v0 : (q == 1) ? v1 : (q == 2) ? v2 : v3;
            const bool b0 = v.x > THRESH, b1 = v.y > THRESH, b2 = v.z > THRESH, b3 = v.w > THRESH;
            const u64 m0 = __ballot(b0);
            const u64 m1 = __ballot(b1);
            const u64 m2 = __ballot(b2);
            const u64 m3 = __ballot(b3);
            if (lane < 4) {
                const u64 m = (lane == 0) ? m0 : (lane == 1) ? m1 : (lane == 2) ? m2 : m3;
                dst[(k << 6) + (wave << 4) + (q << 2) + lane] = m;
            }
            cnt += (int)b0 + (int)b1 + (int)b2 + (int)b3;
            ssum += (b0 ? (double)v.x : 0.0) + (b1 ? (double)v.y : 0.0)
                  + (b2 ? (double)v.z : 0.0) + (b3 ? (double)v.w : 0.0);
        }
    }
    for (int off = 32; off > 0; off >>= 1) {
        ssum += __shfl_down(ssum, off);
        cnt  += __shfl_down(cnt, off);
    }
    __shared__ double ls[4];
    __shared__ int lc[4];
    if (lane == 0) { ls[wave] = ssum; lc[wave] = cnt; }
    __syncthreads();
    if (tid == 0) {
        const double S = ((ls[0] + ls[1]) + ls[2]) + ls[3];
        const int C = ((lc[0] + lc[1]) + lc[2]) + lc[3];
        scoreArr[i] = cate[i] * (float)(S / (double)(C > 1 ? C : 1));
        sumArr[i] = (float)C;
    }
}

// ---------------------------------------------------------------------------
// K2: label-sparse pairwise intersections. Output depends ONLY on same-label
// pairs (~1.3k of 125k at 80 random classes) -> skip 98.8% of dense popcount
// work. Grid-stride waves scan i<j slots with a wave-uniform label filter
// (incremental divmod); a matched pair streams both 8 KB packed masks from
// L2/L3 (coalesced dwordx4), popcount(AND), shuffle-reduce. Lane 0 loads the
// two finalized scores and folds comp in via device-scope atomicMax on IoU
// bits (IoU>=0 -> float bits monotonic; max order-independent ->
// deterministic). inter[] slots for unmatched pairs never written nor read.
// ---------------------------------------------------------------------------
__global__ __launch_bounds__(256) void k_pairs(
    const u64* __restrict__ packed, const float* __restrict__ scoreArr,
    const float* __restrict__ sumArr, const int* __restrict__ labels,
    unsigned* __restrict__ inter, unsigned* __restrict__ compU,
    int N, int WORDS)
{
    const int wid = (blockIdx.x << 2) + (threadIdx.x >> 6);
    const int lane = threadIdx.x & 63;
    const int nw = gridDim.x << 2;
    const int NN = N * N;
    int i = wid / N;
    int j = wid - i * N;
    for (int p = wid; p < NN; p += nw) {
        if (j > i && labels[i] == labels[j]) {
            const u64* A = packed + (size_t)i * WORDS;
            const u64* B = packed + (size_t)j * WORDS;
            unsigned acc = 0;
            const int iters = WORDS >> 7;         // 8: lane covers 2 u64/iter
            #pragma unroll 2
            for (int k = 0; k < iters; ++k) {
                const int idx = (k << 7) + (lane << 1);
                const ulonglong2 a = *reinterpret_cast<const ulonglong2*>(A + idx);
                const ulonglong2 b = *reinterpret_cast<const ulonglong2*>(B + idx);
                acc += (unsigned)__popcll(a.x & b.x) + (unsigned)__popcll(a.y & b.y);
            }
            #pragma unroll
            for (int off = 32; off > 0; off >>= 1) acc += __shfl_down(acc, off);
            if (lane == 0) {
                inter[(size_t)i * N + j] = acc;
                const float si = scoreArr[i], sj = scoreArr[j];
                const int w = better(si, i, sj, j) ? j : i;   // suppressed elem
                // fp32 add commutative -> bit-identical to K3's
                // (s_sum[a] + sub) - inter regardless of which is better.
                const float un = (sumArr[i] + sumArr[j]) - (float)acc;
                const float iou = (float)acc / fmaxf(un, 1.0f);
                atomicMax(&compU[w], __float_as_uint(iou));
            }
        }
        j += nw;
        while (j >= N) { j -= N; ++i; }
    }
}

// ---------------------------------------------------------------------------
// K3: final. m = max over ALL a of (d(a->b)^2 - comp[a]^2), d = (better &&
// label match) ? iou : 0; rank(b) = #better(a,b) in the same loop;
// out[rank(b)] = score[b]*exp(-sigma*m). Ranks are a permutation. LDS fill is
// now just 3 coalesced array loads (scores finalized once in K1).
// ---------------------------------------------------------------------------
__global__ __launch_bounds__(256) void k_final(
    const unsigned* __restrict__ inter, const float* __restrict__ scoreArr,
    const float* __restrict__ sumArr, const int* __restrict__ labels,
    const unsigned* __restrict__ compU, float* __restrict__ out, int N)
{
    __shared__ float s_score[MAXN];
    __shared__ float s_sum[MAXN];
    __shared__ int s_label[MAXN];
    const int tid = threadIdx.x;
    for (int idx = tid; idx < N; idx += 256) {
        s_score[idx] = scoreArr[idx];
        s_sum[idx] = sumArr[idx];
        s_label[idx] = labels[idx];
    }
    __syncthreads();

    const int bI = blockIdx.x;
    const float sb = s_score[bI], sub = s_sum[bI];
    const int lb = s_label[bI];
    float m = -3.0e38f;
    int r = 0;
    for (int a = tid; a < N; a += 256) {
        const bool bet = (a != bI) && better(s_score[a], a, sb, bI);
        r += (int)bet;
        float d = 0.0f;
        if (bet && s_label[a] == lb) {
            const int lo = a < bI ? a : bI, hi = a < bI ? bI : a;
            const float in = (float)inter[(size_t)lo * N + hi];
            const float un = s_sum[a] + sub - in;
            d = in / fmaxf(un, 1.0f);
        }
        const float ca = __uint_as_float(compU[a]);
        m = fmaxf(m, d * d - ca * ca);
    }
    for (int off = 32; off > 0; off >>= 1) {
        m = fmaxf(m, __shfl_down(m, off));
        r += __shfl_down(r, off);
    }
    __shared__ float lm[4];
    __shared__ int lr[4];
    const int wave = tid >> 6, lane = tid & 63;
    if (lane == 0) { lm[wave] = m; lr[wave] = r; }
    __syncthreads();
    if (tid == 0) {
        const float mm = fmaxf(fmaxf(lm[0], lm[1]), fmaxf(lm[2], lm[3]));
        const int rank = lr[0] + lr[1] + lr[2] + lr[3];
        out[rank] = sb * expf(-SIGMA * mm);
    }
}

extern "C" void kernel_launch(void* const* d_in, const int* in_sizes, int n_in,
                              void* d_out, int out_size, void* d_ws, size_t ws_size,
                              hipStream_t stream)
{
    const float* preds  = (const float*)d_in[0];
    const float* cate   = (const float*)d_in[1];
    const int*   labels = (const int*)d_in[2];
    float* out = (float*)d_out;

    const int N = in_sizes[1];
    const int HW = in_sizes[0] / N;
    const int WORDS = HW >> 6;

    char* ws = (char*)d_ws;
    size_t off = 0;
    auto take = [&](size_t bytes) -> void* {
        void* p = ws + off;
        off = (off + bytes + 255) & ~(size_t)255;
        return p;
    };
    u64*      packed   = (u64*)     take((size_t)N * WORDS * sizeof(u64));   // ~4.1 MB
    float*    scoreArr = (float*)   take((size_t)MAXN * sizeof(float));
    float*    sumArr   = (float*)   take((size_t)MAXN * sizeof(float));
    unsigned* compU    = (unsigned*)take((size_t)MAXN * sizeof(unsigned));
    unsigned* inter    = (unsigned*)take((size_t)N * N * sizeof(unsigned));  // ~1 MB
    (void)ws_size; (void)n_in; (void)out_size;

    k_pack<<<N, 256, 0, stream>>>(preds, cate, packed, scoreArr, sumArr, compU, HW);

    k_pairs<<<1024, 256, 0, stream>>>(packed, scoreArr, sumArr, labels,
                                      inter, compU, N, WORDS);

    k_final<<<N, 256, 0, stream>>>(inter, scoreArr, sumArr, labels, compU, out, N);
}